// Round 4
// baseline (280.817 us; speedup 1.0000x reference)
//
#include <hip/hip_runtime.h>
#include <hip/hip_bf16.h>

#define BB 4
#define CC_ 384
#define HH 32
#define WW 32
#define HWSZ 1024
#define NHD 12
#define HCH 32
#define GG 6
#define NGC_ 64
#define GHD 2
#define HK_ 16
#define WK_ 16
#define NS_ 256
#define RPEW 63
#define SCALE_ 0.17677669529663687f

// ---------------- K1/K6: 1x1 conv / batched GEMM (standard layout) ----------------
template<int CIN>
__global__ void conv1x1_kernel(const float* __restrict__ W, const float* __restrict__ bias,
                               const float* __restrict__ X, float* __restrict__ Y,
                               int N, int OC)
{
    const int otile = blockIdx.y * 4;
    const int b = blockIdx.z;
    const int n4 = (blockIdx.x * blockDim.x + threadIdx.x) * 4;
    const float* Xb = X + (size_t)b * CIN * N + n4;
    const float* Wr = W + (size_t)otile * CIN;

    float acc[4][4];
#pragma unroll
    for (int j = 0; j < 4; ++j)
#pragma unroll
        for (int i = 0; i < 4; ++i) acc[j][i] = 0.f;

    for (int c = 0; c < CIN; ++c) {
        float4 xv = *(const float4*)(Xb + (size_t)c * N);
#pragma unroll
        for (int j = 0; j < 4; ++j) {
            float w = Wr[j * CIN + c];
            acc[j][0] = fmaf(w, xv.x, acc[j][0]);
            acc[j][1] = fmaf(w, xv.y, acc[j][1]);
            acc[j][2] = fmaf(w, xv.z, acc[j][2]);
            acc[j][3] = fmaf(w, xv.w, acc[j][3]);
        }
    }
#pragma unroll
    for (int j = 0; j < 4; ++j) {
        int o = otile + j;
        float bv = bias[o];
        float4 r = make_float4(acc[j][0] + bv, acc[j][1] + bv, acc[j][2] + bv, acc[j][3] + bv);
        *(float4*)(Y + ((size_t)(b * OC + o)) * N + n4) = r;
    }
}

// ---------------- K4: 1x1 conv with head-transposed output [bh][n][32] ----------------
template<int CIN>
__global__ void conv1x1t_kernel(const float* __restrict__ W, const float* __restrict__ bias,
                                const float* __restrict__ X, float* __restrict__ Y,
                                int N, int OC)
{
    const int otile = blockIdx.y * 4;          // 4-aligned => same head
    const int b = blockIdx.z;
    const int n4 = (blockIdx.x * blockDim.x + threadIdx.x) * 4;
    const float* Xb = X + (size_t)b * CIN * N + n4;
    const float* Wr = W + (size_t)otile * CIN;

    float acc[4][4];
#pragma unroll
    for (int j = 0; j < 4; ++j)
#pragma unroll
        for (int i = 0; i < 4; ++i) acc[j][i] = 0.f;

    for (int c = 0; c < CIN; ++c) {
        float4 xv = *(const float4*)(Xb + (size_t)c * N);
#pragma unroll
        for (int j = 0; j < 4; ++j) {
            float w = Wr[j * CIN + c];
            acc[j][0] = fmaf(w, xv.x, acc[j][0]);
            acc[j][1] = fmaf(w, xv.y, acc[j][1]);
            acc[j][2] = fmaf(w, xv.z, acc[j][2]);
            acc[j][3] = fmaf(w, xv.w, acc[j][3]);
        }
    }
    const int h = otile >> 5, cc = otile & 31;
    float bv0 = bias[otile + 0], bv1 = bias[otile + 1], bv2 = bias[otile + 2], bv3 = bias[otile + 3];
    float* outp = Y + ((size_t)(b * NHD + h) * N) * 32 + cc;
#pragma unroll
    for (int i = 0; i < 4; ++i) {
        float4 r = make_float4(acc[0][i] + bv0, acc[1][i] + bv1, acc[2][i] + bv2, acc[3][i] + bv3);
        *(float4*)(outp + (size_t)(n4 + i) * 32) = r;
    }
}

// ---------------- K2a: depthwise conv 5x5 stride 2 ----------------
__global__ void offset_dw_kernel(const float* __restrict__ qb, const float* __restrict__ dww,
                                 const float* __restrict__ dwb, float* __restrict__ cobuf)
{
    __shared__ float img[HWSZ];
    const int c = blockIdx.x, bg = blockIdx.y;
    const int b = bg / GG, g = bg - b * GG;
    const int tid = threadIdx.x;
    const float* src = qb + ((size_t)(b * CC_ + g * NGC_ + c)) * HWSZ;
#pragma unroll
    for (int e = tid; e < HWSZ; e += 256) img[e] = src[e];
    __syncthreads();
    const int oy = tid >> 4, ox = tid & 15;
    float s = dwb[c];
    const float* wf = dww + c * 25;
    const int iy0 = oy * 2 - 2, ix0 = ox * 2 - 2;
#pragma unroll
    for (int ky = 0; ky < 5; ++ky) {
        int iy = iy0 + ky;
        if (iy < 0 || iy > 31) continue;
#pragma unroll
        for (int kx = 0; kx < 5; ++kx) {
            int ix = ix0 + kx;
            if (ix < 0 || ix > 31) continue;
            s = fmaf(img[iy * 32 + ix], wf[ky * 5 + kx], s);
        }
    }
    cobuf[((size_t)(bg * NGC_ + c)) * 256 + tid] = s;
}

// ---------------- K2b: LN + GELU + pwconv + tanh -> pos (streaming, no spills) ----------------
__global__ void offset_fin_kernel(const float* __restrict__ cobuf, const float* __restrict__ lng,
                                  const float* __restrict__ lnb, const float* __restrict__ pww,
                                  float* __restrict__ posb)
{
    const int bg = blockIdx.x;
    const int tid = threadIdx.x;
    const int oy = tid >> 4, ox = tid & 15;
    const float* base = cobuf + (size_t)bg * NGC_ * 256 + tid;
    float s1 = 0.f, s2 = 0.f;
#pragma unroll
    for (int c = 0; c < NGC_; ++c) {
        float v = base[(size_t)c * 256];
        s1 += v;
        s2 = fmaf(v, v, s2);
    }
    float mu = s1 * (1.f / 64.f);
    float var = s2 * (1.f / 64.f) - mu * mu;
    float rstd = rsqrtf(var + 1e-5f);
    float o0 = 0.f, o1 = 0.f;
#pragma unroll
    for (int c = 0; c < NGC_; ++c) {
        float v = base[(size_t)c * 256];
        float t = (v - mu) * rstd * lng[c] + lnb[c];
        float gv = 0.5f * t * (1.f + erff(t * 0.70710678118654752f));
        o0 = fmaf(pww[c], gv, o0);
        o1 = fmaf(pww[64 + c], gv, o1);
    }
    float py = tanhf(o0) * (2.f / 15.f) + ((0.5f + (float)oy) * (1.f / 15.f)) * 2.f - 1.f;
    float px = tanhf(o1) * (2.f / 15.f) + ((0.5f + (float)ox) * (1.f / 15.f)) * 2.f - 1.f;
    posb[bg * 512 + tid * 2 + 0] = py;
    posb[bg * 512 + tid * 2 + 1] = px;
}

// ---------------- K3: bilinear KV sampling ----------------
__global__ void sample_xs_kernel(const float* __restrict__ x, const float* __restrict__ posb,
                                 float* __restrict__ xsb)
{
    const int cc = blockIdx.x, bg = blockIdx.y;
    const int b = bg / GG, g = bg - b * GG;
    const int s = threadIdx.x;
    float py = posb[bg * 512 + s * 2 + 0];
    float px = posb[bg * 512 + s * 2 + 1];
    float xi = (px + 1.f) * 0.5f * 31.f;
    float yi = (py + 1.f) * 0.5f * 31.f;
    float x0f = floorf(xi), y0f = floorf(yi);
    int x0 = (int)x0f, y0 = (int)y0f;
    float wx1 = xi - x0f, wy1 = yi - y0f;
    const float* img = x + ((size_t)(b * CC_ + g * NGC_ + cc)) * HWSZ;
    float acc = 0.f;
#pragma unroll
    for (int t = 0; t < 4; ++t) {
        int iy = y0 + (t >> 1), ix = x0 + (t & 1);
        float w = ((t >> 1) ? wy1 : 1.f - wy1) * ((t & 1) ? wx1 : 1.f - wx1);
        if (iy >= 0 && iy <= 31 && ix >= 0 && ix <= 31)
            acc = fmaf(img[iy * 32 + ix], w, acc);
    }
    xsb[((size_t)(b * CC_ + g * NGC_ + cc)) * NS_ + s] = acc;
}

// ---------------- K5: fused attention, global K/V (uniform reads), channel-split ----------------
// grid: (16 qtiles, 48 bh), block 512.
// tid -> half=tid&1 (16 channels), q=(tid>>1)&63, sgrp=tid>>7 (4 groups x 64 samples)
__launch_bounds__(512, 6)
__global__ void attn_kernel(const float* __restrict__ qb, const float* __restrict__ kt,
                            const float* __restrict__ vt, const float* __restrict__ posb,
                            const float* __restrict__ rpe, float* __restrict__ ao)
{
    __shared__ float rp[4096];   // rpe table (3969); reused as ml[1024] + red at +2048 in merge
    __shared__ float ps[512];
    const int bh = blockIdx.y;
    const int b = bh / NHD, h = bh - b * NHD;
    const int bg = b * GG + (h >> 1);
    const int tid = threadIdx.x;

    for (int e = tid; e < RPEW * RPEW; e += 512) rp[e] = rpe[(size_t)h * (RPEW * RPEW) + e];
    ps[tid & 511] = posb[bg * 512 + (tid & 511)];
    __syncthreads();

    const int half = tid & 1;
    const int q = (tid >> 1) & 63;
    const int sgrp = tid >> 7;
    const int qidx = blockIdx.x * 64 + q;
    const int row = qidx >> 5, col = qidx & 31;
    const float gyq = (float)row * (2.f / 31.f) - 1.f;
    const float gxq = (float)col * (2.f / 31.f) - 1.f;

    float qf[16];
    const float* qg = qb + ((size_t)(b * CC_ + h * HCH + half * 16)) * HWSZ + qidx;
#pragma unroll
    for (int c = 0; c < 16; ++c) qf[c] = qg[(size_t)c * HWSZ];

    float m = -3.0e38f, l = 0.f;
    float oacc[16];
#pragma unroll
    for (int c = 0; c < 16; ++c) oacc[c] = 0.f;

    const float* kb2 = kt + ((size_t)bh * NS_) * 32 + half * 16;
    const float* vb2 = vt + ((size_t)bh * NS_) * 32 + half * 16;

    const int s0 = sgrp * 64;
    for (int s = s0; s < s0 + 64; ++s) {
        const float* kr = kb2 + s * 32;
        float4 k0 = *(const float4*)(kr + 0);
        float4 k1 = *(const float4*)(kr + 4);
        float4 k2 = *(const float4*)(kr + 8);
        float4 k3 = *(const float4*)(kr + 12);
        float d0 = 0.f, d1 = 0.f, d2 = 0.f, d3 = 0.f;
        d0 = fmaf(qf[0], k0.x, d0);  d0 = fmaf(qf[1], k0.y, d0);
        d0 = fmaf(qf[2], k0.z, d0);  d0 = fmaf(qf[3], k0.w, d0);
        d1 = fmaf(qf[4], k1.x, d1);  d1 = fmaf(qf[5], k1.y, d1);
        d1 = fmaf(qf[6], k1.z, d1);  d1 = fmaf(qf[7], k1.w, d1);
        d2 = fmaf(qf[8], k2.x, d2);  d2 = fmaf(qf[9], k2.y, d2);
        d2 = fmaf(qf[10], k2.z, d2); d2 = fmaf(qf[11], k2.w, d2);
        d3 = fmaf(qf[12], k3.x, d3); d3 = fmaf(qf[13], k3.y, d3);
        d3 = fmaf(qf[14], k3.z, d3); d3 = fmaf(qf[15], k3.w, d3);
        float dh = (d0 + d1) + (d2 + d3);
        float dsum = dh + __shfl_xor(dh, 1);

        float py = ps[s * 2 + 0], px = ps[s * 2 + 1];
        float dy = (gyq - py) * 0.5f, dx = (gxq - px) * 0.5f;
        float yi = (dy + 1.f) * 31.f, xi = (dx + 1.f) * 31.f;
        float y0f = floorf(yi), x0f = floorf(xi);
        int y0 = (int)y0f, x0 = (int)x0f;
        float wy1 = yi - y0f, wx1 = xi - x0f;
        float bias = 0.f;
#pragma unroll
        for (int tt = 0; tt < 4; ++tt) {
            int iy = y0 + (tt >> 1), ix = x0 + (tt & 1);
            float wgt = ((tt >> 1) ? wy1 : 1.f - wy1) * ((tt & 1) ? wx1 : 1.f - wx1);
            if (iy >= 0 && iy <= 62 && ix >= 0 && ix <= 62)
                bias = fmaf(rp[iy * 63 + ix], wgt, bias);
        }
        float logit = fmaf(dsum, SCALE_, bias);
        // defer-max: rescale only when some lane exceeds m+8 (rare after warm-up)
        if (__any(logit > m + 8.f)) {
            if (logit > m) {
                float corr = __expf(m - logit);
                l *= corr;
#pragma unroll
                for (int c = 0; c < 16; ++c) oacc[c] *= corr;
                m = logit;
            }
        }
        float p = __expf(logit - m);
        l += p;
        const float* vr = vb2 + s * 32;
        float4 v0 = *(const float4*)(vr + 0);
        float4 v1 = *(const float4*)(vr + 4);
        float4 v2 = *(const float4*)(vr + 8);
        float4 v3 = *(const float4*)(vr + 12);
        oacc[0]  = fmaf(p, v0.x, oacc[0]);  oacc[1]  = fmaf(p, v0.y, oacc[1]);
        oacc[2]  = fmaf(p, v0.z, oacc[2]);  oacc[3]  = fmaf(p, v0.w, oacc[3]);
        oacc[4]  = fmaf(p, v1.x, oacc[4]);  oacc[5]  = fmaf(p, v1.y, oacc[5]);
        oacc[6]  = fmaf(p, v1.z, oacc[6]);  oacc[7]  = fmaf(p, v1.w, oacc[7]);
        oacc[8]  = fmaf(p, v2.x, oacc[8]);  oacc[9]  = fmaf(p, v2.y, oacc[9]);
        oacc[10] = fmaf(p, v2.z, oacc[10]); oacc[11] = fmaf(p, v2.w, oacc[11]);
        oacc[12] = fmaf(p, v3.x, oacc[12]); oacc[13] = fmaf(p, v3.y, oacc[13]);
        oacc[14] = fmaf(p, v3.z, oacc[14]); oacc[15] = fmaf(p, v3.w, oacc[15]);
    }

    // ---- merge 4 sample-groups (rp region is dead now) ----
    __syncthreads();
    float* ml = rp;
    ml[tid * 2 + 0] = m;
    ml[tid * 2 + 1] = l;
    __syncthreads();
    const int mbase = tid & 127;
    float m0 = ml[(mbase + 0) * 2],   l0 = ml[(mbase + 0) * 2 + 1];
    float m1 = ml[(mbase + 128) * 2], l1 = ml[(mbase + 128) * 2 + 1];
    float m2 = ml[(mbase + 256) * 2], l2 = ml[(mbase + 256) * 2 + 1];
    float m3 = ml[(mbase + 384) * 2], l3 = ml[(mbase + 384) * 2 + 1];
    float mstar = fmaxf(fmaxf(m0, m1), fmaxf(m2, m3));
    float L = l0 * __expf(m0 - mstar) + l1 * __expf(m1 - mstar)
            + l2 * __expf(m2 - mstar) + l3 * __expf(m3 - mstar);
    float scale = __expf(m - mstar) / L;

    float4* red = (float4*)(rp + 2048);
    float* og = ao + ((size_t)(b * CC_ + h * HCH + half * 16)) * HWSZ + qidx;
#pragma unroll
    for (int cb = 0; cb < 4; ++cb) {
        __syncthreads();
        red[tid] = make_float4(oacc[cb * 4 + 0] * scale, oacc[cb * 4 + 1] * scale,
                               oacc[cb * 4 + 2] * scale, oacc[cb * 4 + 3] * scale);
        __syncthreads();
        if (sgrp == 0) {
            float4 a = red[tid], b4 = red[tid + 128], c4 = red[tid + 256], d4 = red[tid + 384];
            float4 sm = make_float4(a.x + b4.x + c4.x + d4.x, a.y + b4.y + c4.y + d4.y,
                                    a.z + b4.z + c4.z + d4.z, a.w + b4.w + c4.w + d4.w);
            og[(size_t)(cb * 4 + 0) * HWSZ] = sm.x;
            og[(size_t)(cb * 4 + 1) * HWSZ] = sm.y;
            og[(size_t)(cb * 4 + 2) * HWSZ] = sm.z;
            og[(size_t)(cb * 4 + 3) * HWSZ] = sm.w;
        }
    }
}

extern "C" void kernel_launch(void* const* d_in, const int* in_sizes, int n_in,
                              void* d_out, int out_size, void* d_ws, size_t ws_size,
                              hipStream_t stream) {
    (void)in_sizes; (void)n_in; (void)out_size; (void)ws_size;
    const float* x   = (const float*)d_in[0];
    const float* Wq  = (const float*)d_in[1];
    const float* bq  = (const float*)d_in[2];
    const float* Wk  = (const float*)d_in[3];
    const float* bk  = (const float*)d_in[4];
    const float* Wv  = (const float*)d_in[5];
    const float* bv  = (const float*)d_in[6];
    const float* Wo  = (const float*)d_in[7];
    const float* bo  = (const float*)d_in[8];
    const float* dww = (const float*)d_in[9];
    const float* dwb = (const float*)d_in[10];
    const float* lng = (const float*)d_in[11];
    const float* lnb = (const float*)d_in[12];
    const float* pww = (const float*)d_in[13];
    const float* rpe = (const float*)d_in[14];
    float* out = (float*)d_out;

    float* ws   = (float*)d_ws;
    float* qbuf = ws;                       // 1572864
    float* posb = qbuf + 1572864;           // 12288
    float* xsb  = posb + 12288;             // 393216
    float* ktb  = xsb + 393216;             // 393216 [bh][s][32]
    float* vtb  = ktb + 393216;             // 393216 [bh][s][32]
    float* aout = vtb + 393216;             // 1572864
    float* cobuf = aout;                    // 393216, dead before attn writes aout

    conv1x1_kernel<CC_><<<dim3(1, CC_ / 4, BB), 256, 0, stream>>>(Wq, bq, x, qbuf, HWSZ, CC_);
    offset_dw_kernel<<<dim3(NGC_, 24), 256, 0, stream>>>(qbuf, dww, dwb, cobuf);
    offset_fin_kernel<<<dim3(24), 256, 0, stream>>>(cobuf, lng, lnb, pww, posb);
    sample_xs_kernel<<<dim3(NGC_, 24), 256, 0, stream>>>(x, posb, xsb);
    conv1x1t_kernel<CC_><<<dim3(1, CC_ / 4, BB), 64, 0, stream>>>(Wk, bk, xsb, ktb, NS_, CC_);
    conv1x1t_kernel<CC_><<<dim3(1, CC_ / 4, BB), 64, 0, stream>>>(Wv, bv, xsb, vtb, NS_, CC_);
    attn_kernel<<<dim3(16, BB * NHD), 512, 0, stream>>>(qbuf, ktb, vtb, posb, rpe, aout);
    conv1x1_kernel<CC_><<<dim3(1, CC_ / 4, BB), 256, 0, stream>>>(Wo, bo, aout, out, HWSZ, CC_);
}

// Round 5
// 248.291 us; speedup vs baseline: 1.1310x; 1.1310x over previous
//
#include <hip/hip_runtime.h>
#include <hip/hip_bf16.h>

#define BB 4
#define CC_ 384
#define HH 32
#define WW 32
#define HWSZ 1024
#define NHD 12
#define HCH 32
#define GG 6
#define NGC_ 64
#define GHD 2
#define HK_ 16
#define WK_ 16
#define NS_ 256
#define RPEW 63
#define SCALE_ 0.17677669529663687f

// ---------------- K1/K6: 1x1 conv / batched GEMM (standard layout) ----------------
template<int CIN>
__global__ void conv1x1_kernel(const float* __restrict__ W, const float* __restrict__ bias,
                               const float* __restrict__ X, float* __restrict__ Y,
                               int N, int OC)
{
    const int otile = blockIdx.y * 4;
    const int b = blockIdx.z;
    const int n4 = (blockIdx.x * blockDim.x + threadIdx.x) * 4;
    const float* Xb = X + (size_t)b * CIN * N + n4;
    const float* Wr = W + (size_t)otile * CIN;

    float acc[4][4];
#pragma unroll
    for (int j = 0; j < 4; ++j)
#pragma unroll
        for (int i = 0; i < 4; ++i) acc[j][i] = 0.f;

    for (int c = 0; c < CIN; ++c) {
        float4 xv = *(const float4*)(Xb + (size_t)c * N);
#pragma unroll
        for (int j = 0; j < 4; ++j) {
            float w = Wr[j * CIN + c];
            acc[j][0] = fmaf(w, xv.x, acc[j][0]);
            acc[j][1] = fmaf(w, xv.y, acc[j][1]);
            acc[j][2] = fmaf(w, xv.z, acc[j][2]);
            acc[j][3] = fmaf(w, xv.w, acc[j][3]);
        }
    }
#pragma unroll
    for (int j = 0; j < 4; ++j) {
        int o = otile + j;
        float bv = bias[o];
        float4 r = make_float4(acc[j][0] + bv, acc[j][1] + bv, acc[j][2] + bv, acc[j][3] + bv);
        *(float4*)(Y + ((size_t)(b * OC + o)) * N + n4) = r;
    }
}

// ---------------- K4: 1x1 conv with head-transposed output [bh][n][32] ----------------
template<int CIN>
__global__ void conv1x1t_kernel(const float* __restrict__ W, const float* __restrict__ bias,
                                const float* __restrict__ X, float* __restrict__ Y,
                                int N, int OC)
{
    const int otile = blockIdx.y * 4;          // 4-aligned => same head
    const int b = blockIdx.z;
    const int n4 = (blockIdx.x * blockDim.x + threadIdx.x) * 4;
    const float* Xb = X + (size_t)b * CIN * N + n4;
    const float* Wr = W + (size_t)otile * CIN;

    float acc[4][4];
#pragma unroll
    for (int j = 0; j < 4; ++j)
#pragma unroll
        for (int i = 0; i < 4; ++i) acc[j][i] = 0.f;

    for (int c = 0; c < CIN; ++c) {
        float4 xv = *(const float4*)(Xb + (size_t)c * N);
#pragma unroll
        for (int j = 0; j < 4; ++j) {
            float w = Wr[j * CIN + c];
            acc[j][0] = fmaf(w, xv.x, acc[j][0]);
            acc[j][1] = fmaf(w, xv.y, acc[j][1]);
            acc[j][2] = fmaf(w, xv.z, acc[j][2]);
            acc[j][3] = fmaf(w, xv.w, acc[j][3]);
        }
    }
    const int h = otile >> 5, cc = otile & 31;
    float bv0 = bias[otile + 0], bv1 = bias[otile + 1], bv2 = bias[otile + 2], bv3 = bias[otile + 3];
    float* outp = Y + ((size_t)(b * NHD + h) * N) * 32 + cc;
#pragma unroll
    for (int i = 0; i < 4; ++i) {
        float4 r = make_float4(acc[0][i] + bv0, acc[1][i] + bv1, acc[2][i] + bv2, acc[3][i] + bv3);
        *(float4*)(outp + (size_t)(n4 + i) * 32) = r;
    }
}

// ---------------- K2a: depthwise conv 5x5 stride 2 ----------------
__global__ void offset_dw_kernel(const float* __restrict__ qb, const float* __restrict__ dww,
                                 const float* __restrict__ dwb, float* __restrict__ cobuf)
{
    __shared__ float img[HWSZ];
    const int c = blockIdx.x, bg = blockIdx.y;
    const int b = bg / GG, g = bg - b * GG;
    const int tid = threadIdx.x;
    const float* src = qb + ((size_t)(b * CC_ + g * NGC_ + c)) * HWSZ;
#pragma unroll
    for (int e = tid; e < HWSZ; e += 256) img[e] = src[e];
    __syncthreads();
    const int oy = tid >> 4, ox = tid & 15;
    float s = dwb[c];
    const float* wf = dww + c * 25;
    const int iy0 = oy * 2 - 2, ix0 = ox * 2 - 2;
#pragma unroll
    for (int ky = 0; ky < 5; ++ky) {
        int iy = iy0 + ky;
        if (iy < 0 || iy > 31) continue;
#pragma unroll
        for (int kx = 0; kx < 5; ++kx) {
            int ix = ix0 + kx;
            if (ix < 0 || ix > 31) continue;
            s = fmaf(img[iy * 32 + ix], wf[ky * 5 + kx], s);
        }
    }
    cobuf[((size_t)(bg * NGC_ + c)) * 256 + tid] = s;
}

// ---------------- K2b: LN + GELU + pwconv + tanh -> pos (streaming, no spills) ----------------
__global__ void offset_fin_kernel(const float* __restrict__ cobuf, const float* __restrict__ lng,
                                  const float* __restrict__ lnb, const float* __restrict__ pww,
                                  float* __restrict__ posb)
{
    const int bg = blockIdx.x;
    const int tid = threadIdx.x;
    const int oy = tid >> 4, ox = tid & 15;
    const float* base = cobuf + (size_t)bg * NGC_ * 256 + tid;
    float s1 = 0.f, s2 = 0.f;
#pragma unroll
    for (int c = 0; c < NGC_; ++c) {
        float v = base[(size_t)c * 256];
        s1 += v;
        s2 = fmaf(v, v, s2);
    }
    float mu = s1 * (1.f / 64.f);
    float var = s2 * (1.f / 64.f) - mu * mu;
    float rstd = rsqrtf(var + 1e-5f);
    float o0 = 0.f, o1 = 0.f;
#pragma unroll
    for (int c = 0; c < NGC_; ++c) {
        float v = base[(size_t)c * 256];
        float t = (v - mu) * rstd * lng[c] + lnb[c];
        float gv = 0.5f * t * (1.f + erff(t * 0.70710678118654752f));
        o0 = fmaf(pww[c], gv, o0);
        o1 = fmaf(pww[64 + c], gv, o1);
    }
    float py = tanhf(o0) * (2.f / 15.f) + ((0.5f + (float)oy) * (1.f / 15.f)) * 2.f - 1.f;
    float px = tanhf(o1) * (2.f / 15.f) + ((0.5f + (float)ox) * (1.f / 15.f)) * 2.f - 1.f;
    posb[bg * 512 + tid * 2 + 0] = py;
    posb[bg * 512 + tid * 2 + 1] = px;
}

// ---------------- K3: bilinear KV sampling ----------------
__global__ void sample_xs_kernel(const float* __restrict__ x, const float* __restrict__ posb,
                                 float* __restrict__ xsb)
{
    const int cc = blockIdx.x, bg = blockIdx.y;
    const int b = bg / GG, g = bg - b * GG;
    const int s = threadIdx.x;
    float py = posb[bg * 512 + s * 2 + 0];
    float px = posb[bg * 512 + s * 2 + 1];
    float xi = (px + 1.f) * 0.5f * 31.f;
    float yi = (py + 1.f) * 0.5f * 31.f;
    float x0f = floorf(xi), y0f = floorf(yi);
    int x0 = (int)x0f, y0 = (int)y0f;
    float wx1 = xi - x0f, wy1 = yi - y0f;
    const float* img = x + ((size_t)(b * CC_ + g * NGC_ + cc)) * HWSZ;
    float acc = 0.f;
#pragma unroll
    for (int t = 0; t < 4; ++t) {
        int iy = y0 + (t >> 1), ix = x0 + (t & 1);
        float w = ((t >> 1) ? wy1 : 1.f - wy1) * ((t & 1) ? wx1 : 1.f - wx1);
        if (iy >= 0 && iy <= 31 && ix >= 0 && ix <= 31)
            acc = fmaf(img[iy * 32 + ix], w, acc);
    }
    xsb[((size_t)(b * CC_ + g * NGC_ + cc)) * NS_ + s] = acc;
}

// ---------------- K5: fused attention, K/V via wave-uniform scalar loads ----------------
// grid: (16 qtiles, 48 bh), block 256 = 64 queries(lanes) x 4 sample-group waves.
// K/V rows are wave-uniform per sample -> SGPR s_load; dot/PV = v_fma(v, s, v).
__launch_bounds__(256, 4)
__global__ void attn_kernel(const float* __restrict__ qb, const float* __restrict__ kt,
                            const float* __restrict__ vt, const float* __restrict__ posb,
                            const float* __restrict__ rpe, float* __restrict__ ao)
{
    __shared__ float rp[4096];   // rpe (3969); reused: ml[512] at 0, red float4[256] at +2048
    __shared__ float ps[512];
    const int bh = blockIdx.y;
    const int b = bh / NHD, h = bh - b * NHD;
    const int bg = b * GG + (h >> 1);
    const int tid = threadIdx.x;

    for (int e = tid; e < RPEW * RPEW; e += 256) rp[e] = rpe[(size_t)h * (RPEW * RPEW) + e];
    for (int e = tid; e < 512; e += 256) ps[e] = posb[bg * 512 + e];
    __syncthreads();

    const int q = tid & 63;
    const int sgrp = __builtin_amdgcn_readfirstlane(tid >> 6);  // wave-uniform in SGPR
    const int qidx = blockIdx.x * 64 + q;
    const int row = qidx >> 5, col = qidx & 31;
    const float gyq = (float)row * (2.f / 31.f) - 1.f;
    const float gxq = (float)col * (2.f / 31.f) - 1.f;

    float qf[32];
    const float* qg = qb + ((size_t)(b * CC_ + h * HCH)) * HWSZ + qidx;
#pragma unroll
    for (int c = 0; c < 32; ++c) qf[c] = qg[(size_t)c * HWSZ];

    float m = -3.0e38f, l = 0.f;
    float oacc[32];
#pragma unroll
    for (int c = 0; c < 32; ++c) oacc[c] = 0.f;

    const float* kb2 = kt + ((size_t)bh * NS_) * 32;
    const float* vb2 = vt + ((size_t)bh * NS_) * 32;

    const int s0 = sgrp * 64;
#pragma unroll 2
    for (int s = s0; s < s0 + 64; ++s) {
        const float* kr = kb2 + s * 32;   // wave-uniform -> s_load
        float d0 = 0.f, d1 = 0.f, d2 = 0.f, d3 = 0.f;
#pragma unroll
        for (int c8 = 0; c8 < 4; ++c8) {
            const int o = c8 * 8;
            float k0 = kr[o + 0], k1 = kr[o + 1], k2 = kr[o + 2], k3 = kr[o + 3];
            float k4 = kr[o + 4], k5 = kr[o + 5], k6 = kr[o + 6], k7 = kr[o + 7];
            d0 = fmaf(qf[o + 0], k0, d0); d1 = fmaf(qf[o + 1], k1, d1);
            d2 = fmaf(qf[o + 2], k2, d2); d3 = fmaf(qf[o + 3], k3, d3);
            d0 = fmaf(qf[o + 4], k4, d0); d1 = fmaf(qf[o + 5], k5, d1);
            d2 = fmaf(qf[o + 6], k6, d2); d3 = fmaf(qf[o + 7], k7, d3);
        }
        float dot = (d0 + d1) + (d2 + d3);

        float py = ps[s * 2 + 0], px = ps[s * 2 + 1];
        float dy = (gyq - py) * 0.5f, dx = (gxq - px) * 0.5f;
        float yi = (dy + 1.f) * 31.f, xi = (dx + 1.f) * 31.f;
        float y0f = floorf(yi), x0f = floorf(xi);
        int y0 = (int)y0f, x0 = (int)x0f;
        float wy1 = yi - y0f, wx1 = xi - x0f;
        float bias = 0.f;
#pragma unroll
        for (int tt = 0; tt < 4; ++tt) {
            int iy = y0 + (tt >> 1), ix = x0 + (tt & 1);
            float wgt = ((tt >> 1) ? wy1 : 1.f - wy1) * ((tt & 1) ? wx1 : 1.f - wx1);
            if (iy >= 0 && iy <= 62 && ix >= 0 && ix <= 62)
                bias = fmaf(rp[iy * 63 + ix], wgt, bias);
        }
        float logit = fmaf(dot, SCALE_, bias);
        if (logit > m) {
            float corr = __expf(m - logit);
            l *= corr;
#pragma unroll
            for (int c = 0; c < 32; ++c) oacc[c] *= corr;
            m = logit;
        }
        float p = __expf(logit - m);
        l += p;
        const float* vr = vb2 + s * 32;   // wave-uniform -> s_load
#pragma unroll
        for (int c8 = 0; c8 < 4; ++c8) {
            const int o = c8 * 8;
            float v0 = vr[o + 0], v1 = vr[o + 1], v2 = vr[o + 2], v3 = vr[o + 3];
            float v4 = vr[o + 4], v5 = vr[o + 5], v6 = vr[o + 6], v7 = vr[o + 7];
            oacc[o + 0] = fmaf(p, v0, oacc[o + 0]); oacc[o + 1] = fmaf(p, v1, oacc[o + 1]);
            oacc[o + 2] = fmaf(p, v2, oacc[o + 2]); oacc[o + 3] = fmaf(p, v3, oacc[o + 3]);
            oacc[o + 4] = fmaf(p, v4, oacc[o + 4]); oacc[o + 5] = fmaf(p, v5, oacc[o + 5]);
            oacc[o + 6] = fmaf(p, v6, oacc[o + 6]); oacc[o + 7] = fmaf(p, v7, oacc[o + 7]);
        }
    }

    // ---- merge 4 sample-group waves (rp dead now) ----
    __syncthreads();
    float* ml = rp;
    ml[tid * 2 + 0] = m;
    ml[tid * 2 + 1] = l;
    __syncthreads();
    float m0 = ml[(q + 0) * 2],   l0 = ml[(q + 0) * 2 + 1];
    float m1 = ml[(q + 64) * 2],  l1 = ml[(q + 64) * 2 + 1];
    float m2 = ml[(q + 128) * 2], l2 = ml[(q + 128) * 2 + 1];
    float m3 = ml[(q + 192) * 2], l3 = ml[(q + 192) * 2 + 1];
    float mstar = fmaxf(fmaxf(m0, m1), fmaxf(m2, m3));
    float L = l0 * __expf(m0 - mstar) + l1 * __expf(m1 - mstar)
            + l2 * __expf(m2 - mstar) + l3 * __expf(m3 - mstar);
    float scale = __expf(m - mstar) / L;

    float4* red = (float4*)(rp + 2048);
    float* og = ao + ((size_t)(b * CC_ + h * HCH)) * HWSZ + qidx;
#pragma unroll
    for (int cb = 0; cb < 8; ++cb) {
        __syncthreads();
        red[tid] = make_float4(oacc[cb * 4 + 0] * scale, oacc[cb * 4 + 1] * scale,
                               oacc[cb * 4 + 2] * scale, oacc[cb * 4 + 3] * scale);
        __syncthreads();
        if (sgrp == 0) {
            float4 a = red[q], b4 = red[q + 64], c4 = red[q + 128], d4 = red[q + 192];
            float4 sm = make_float4(a.x + b4.x + c4.x + d4.x, a.y + b4.y + c4.y + d4.y,
                                    a.z + b4.z + c4.z + d4.z, a.w + b4.w + c4.w + d4.w);
            og[(size_t)(cb * 4 + 0) * HWSZ] = sm.x;
            og[(size_t)(cb * 4 + 1) * HWSZ] = sm.y;
            og[(size_t)(cb * 4 + 2) * HWSZ] = sm.z;
            og[(size_t)(cb * 4 + 3) * HWSZ] = sm.w;
        }
    }
}

extern "C" void kernel_launch(void* const* d_in, const int* in_sizes, int n_in,
                              void* d_out, int out_size, void* d_ws, size_t ws_size,
                              hipStream_t stream) {
    (void)in_sizes; (void)n_in; (void)out_size; (void)ws_size;
    const float* x   = (const float*)d_in[0];
    const float* Wq  = (const float*)d_in[1];
    const float* bq  = (const float*)d_in[2];
    const float* Wk  = (const float*)d_in[3];
    const float* bk  = (const float*)d_in[4];
    const float* Wv  = (const float*)d_in[5];
    const float* bv  = (const float*)d_in[6];
    const float* Wo  = (const float*)d_in[7];
    const float* bo  = (const float*)d_in[8];
    const float* dww = (const float*)d_in[9];
    const float* dwb = (const float*)d_in[10];
    const float* lng = (const float*)d_in[11];
    const float* lnb = (const float*)d_in[12];
    const float* pww = (const float*)d_in[13];
    const float* rpe = (const float*)d_in[14];
    float* out = (float*)d_out;

    float* ws   = (float*)d_ws;
    float* qbuf = ws;                       // 1572864
    float* posb = qbuf + 1572864;           // 12288
    float* xsb  = posb + 12288;             // 393216
    float* ktb  = xsb + 393216;             // 393216 [bh][s][32]
    float* vtb  = ktb + 393216;             // 393216 [bh][s][32]
    float* aout = vtb + 393216;             // 1572864
    float* cobuf = aout;                    // 393216, dead before attn writes aout

    conv1x1_kernel<CC_><<<dim3(1, CC_ / 4, BB), 256, 0, stream>>>(Wq, bq, x, qbuf, HWSZ, CC_);
    offset_dw_kernel<<<dim3(NGC_, 24), 256, 0, stream>>>(qbuf, dww, dwb, cobuf);
    offset_fin_kernel<<<dim3(24), 256, 0, stream>>>(cobuf, lng, lnb, pww, posb);
    sample_xs_kernel<<<dim3(NGC_, 24), 256, 0, stream>>>(x, posb, xsb);
    conv1x1t_kernel<CC_><<<dim3(1, CC_ / 4, BB), 64, 0, stream>>>(Wk, bk, xsb, ktb, NS_, CC_);
    conv1x1t_kernel<CC_><<<dim3(1, CC_ / 4, BB), 64, 0, stream>>>(Wv, bv, xsb, vtb, NS_, CC_);
    attn_kernel<<<dim3(16, BB * NHD), 256, 0, stream>>>(qbuf, ktb, vtb, posb, rpe, aout);
    conv1x1_kernel<CC_><<<dim3(1, CC_ / 4, BB), 256, 0, stream>>>(Wo, bo, aout, out, HWSZ, CC_);
}

// Round 6
// 217.178 us; speedup vs baseline: 1.2930x; 1.1433x over previous
//
#include <hip/hip_runtime.h>
#include <hip/hip_bf16.h>

#define BB 4
#define CC_ 384
#define HH 32
#define WW 32
#define HWSZ 1024
#define NHD 12
#define HCH 32
#define GG 6
#define NGC_ 64
#define GHD 2
#define HK_ 16
#define WK_ 16
#define NS_ 256
#define RPEW 63
#define SCALE_ 0.17677669529663687f

// ---------------- K1/K6: 1x1 conv / batched GEMM (standard layout) ----------------
template<int CIN>
__global__ void conv1x1_kernel(const float* __restrict__ W, const float* __restrict__ bias,
                               const float* __restrict__ X, float* __restrict__ Y,
                               int N, int OC)
{
    const int otile = blockIdx.y * 4;
    const int b = blockIdx.z;
    const int n4 = (blockIdx.x * blockDim.x + threadIdx.x) * 4;
    const float* Xb = X + (size_t)b * CIN * N + n4;
    const float* Wr = W + (size_t)otile * CIN;

    float acc[4][4];
#pragma unroll
    for (int j = 0; j < 4; ++j)
#pragma unroll
        for (int i = 0; i < 4; ++i) acc[j][i] = 0.f;

    for (int c = 0; c < CIN; ++c) {
        float4 xv = *(const float4*)(Xb + (size_t)c * N);
#pragma unroll
        for (int j = 0; j < 4; ++j) {
            float w = Wr[j * CIN + c];
            acc[j][0] = fmaf(w, xv.x, acc[j][0]);
            acc[j][1] = fmaf(w, xv.y, acc[j][1]);
            acc[j][2] = fmaf(w, xv.z, acc[j][2]);
            acc[j][3] = fmaf(w, xv.w, acc[j][3]);
        }
    }
#pragma unroll
    for (int j = 0; j < 4; ++j) {
        int o = otile + j;
        float bv = bias[o];
        float4 r = make_float4(acc[j][0] + bv, acc[j][1] + bv, acc[j][2] + bv, acc[j][3] + bv);
        *(float4*)(Y + ((size_t)(b * OC + o)) * N + n4) = r;
    }
}

// ---------------- K4: 1x1 conv with head-transposed output [bh][n][32] ----------------
template<int CIN>
__global__ void conv1x1t_kernel(const float* __restrict__ W, const float* __restrict__ bias,
                                const float* __restrict__ X, float* __restrict__ Y,
                                int N, int OC)
{
    const int otile = blockIdx.y * 4;          // 4-aligned => same head
    const int b = blockIdx.z;
    const int n4 = (blockIdx.x * blockDim.x + threadIdx.x) * 4;
    const float* Xb = X + (size_t)b * CIN * N + n4;
    const float* Wr = W + (size_t)otile * CIN;

    float acc[4][4];
#pragma unroll
    for (int j = 0; j < 4; ++j)
#pragma unroll
        for (int i = 0; i < 4; ++i) acc[j][i] = 0.f;

    for (int c = 0; c < CIN; ++c) {
        float4 xv = *(const float4*)(Xb + (size_t)c * N);
#pragma unroll
        for (int j = 0; j < 4; ++j) {
            float w = Wr[j * CIN + c];
            acc[j][0] = fmaf(w, xv.x, acc[j][0]);
            acc[j][1] = fmaf(w, xv.y, acc[j][1]);
            acc[j][2] = fmaf(w, xv.z, acc[j][2]);
            acc[j][3] = fmaf(w, xv.w, acc[j][3]);
        }
    }
    const int h = otile >> 5, cc = otile & 31;
    float bv0 = bias[otile + 0], bv1 = bias[otile + 1], bv2 = bias[otile + 2], bv3 = bias[otile + 3];
    float* outp = Y + ((size_t)(b * NHD + h) * N) * 32 + cc;
#pragma unroll
    for (int i = 0; i < 4; ++i) {
        float4 r = make_float4(acc[0][i] + bv0, acc[1][i] + bv1, acc[2][i] + bv2, acc[3][i] + bv3);
        *(float4*)(outp + (size_t)(n4 + i) * 32) = r;
    }
}

// ---------------- K2a: depthwise conv 5x5 stride 2, transposed output [bg][pos][ch] ----------------
__global__ void offset_dw_kernel(const float* __restrict__ qb, const float* __restrict__ dww,
                                 const float* __restrict__ dwb, float* __restrict__ cobuf)
{
    __shared__ float img[HWSZ];
    const int c = blockIdx.x, bg = blockIdx.y;
    const int b = bg / GG, g = bg - b * GG;
    const int tid = threadIdx.x;
    const float* src = qb + ((size_t)(b * CC_ + g * NGC_ + c)) * HWSZ;
#pragma unroll
    for (int e = tid; e < HWSZ; e += 256) img[e] = src[e];
    __syncthreads();
    const int oy = tid >> 4, ox = tid & 15;
    float s = dwb[c];
    const float* wf = dww + c * 25;
    const int iy0 = oy * 2 - 2, ix0 = ox * 2 - 2;
#pragma unroll
    for (int ky = 0; ky < 5; ++ky) {
        int iy = iy0 + ky;
        if (iy < 0 || iy > 31) continue;
#pragma unroll
        for (int kx = 0; kx < 5; ++kx) {
            int ix = ix0 + kx;
            if (ix < 0 || ix > 31) continue;
            s = fmaf(img[iy * 32 + ix], wf[ky * 5 + kx], s);
        }
    }
    cobuf[((size_t)(bg * 256 + tid)) * NGC_ + c] = s;   // [bg][pos][ch]
}

// ---------------- K2b: LN + GELU + pw + tanh, one wave per position ----------------
// grid: 1536 blocks x 256 thr; wave w handles global position blockIdx*4+w; lane = channel
__global__ void offset_fin_kernel(const float* __restrict__ cobuf, const float* __restrict__ lng,
                                  const float* __restrict__ lnb, const float* __restrict__ pww,
                                  float* __restrict__ posb)
{
    const int lane = threadIdx.x & 63;
    const int gpos = blockIdx.x * 4 + (threadIdx.x >> 6);   // 0..6143
    const int bg = gpos >> 8, pos = gpos & 255;
    const int oy = (pos >> 4), ox = pos & 15;

    float v = cobuf[(size_t)gpos * NGC_ + lane];
    float s1 = v, s2 = v * v;
#pragma unroll
    for (int off = 32; off >= 1; off >>= 1) {
        s1 += __shfl_xor(s1, off);
        s2 += __shfl_xor(s2, off);
    }
    float mu = s1 * (1.f / 64.f);
    float var = s2 * (1.f / 64.f) - mu * mu;
    float rstd = rsqrtf(var + 1e-5f);
    float t = (v - mu) * rstd * lng[lane] + lnb[lane];
    float gv = 0.5f * t * (1.f + erff(t * 0.70710678118654752f));
    float o0 = pww[lane] * gv;
    float o1 = pww[64 + lane] * gv;
#pragma unroll
    for (int off = 32; off >= 1; off >>= 1) {
        o0 += __shfl_xor(o0, off);
        o1 += __shfl_xor(o1, off);
    }
    if (lane == 0) {
        float py = tanhf(o0) * (2.f / 15.f) + ((0.5f + (float)oy) * (1.f / 15.f)) * 2.f - 1.f;
        float px = tanhf(o1) * (2.f / 15.f) + ((0.5f + (float)ox) * (1.f / 15.f)) * 2.f - 1.f;
        posb[bg * 512 + pos * 2 + 0] = py;
        posb[bg * 512 + pos * 2 + 1] = px;
    }
}

// ---------------- K3: bilinear KV sampling ----------------
__global__ void sample_xs_kernel(const float* __restrict__ x, const float* __restrict__ posb,
                                 float* __restrict__ xsb)
{
    const int cc = blockIdx.x, bg = blockIdx.y;
    const int b = bg / GG, g = bg - b * GG;
    const int s = threadIdx.x;
    float py = posb[bg * 512 + s * 2 + 0];
    float px = posb[bg * 512 + s * 2 + 1];
    float xi = (px + 1.f) * 0.5f * 31.f;
    float yi = (py + 1.f) * 0.5f * 31.f;
    float x0f = floorf(xi), y0f = floorf(yi);
    int x0 = (int)x0f, y0 = (int)y0f;
    float wx1 = xi - x0f, wy1 = yi - y0f;
    const float* img = x + ((size_t)(b * CC_ + g * NGC_ + cc)) * HWSZ;
    float acc = 0.f;
#pragma unroll
    for (int t = 0; t < 4; ++t) {
        int iy = y0 + (t >> 1), ix = x0 + (t & 1);
        float w = ((t >> 1) ? wy1 : 1.f - wy1) * ((t & 1) ? wx1 : 1.f - wx1);
        if (iy >= 0 && iy <= 31 && ix >= 0 && ix <= 31)
            acc = fmaf(img[iy * 32 + ix], w, acc);
    }
    xsb[((size_t)(b * CC_ + g * NGC_ + cc)) * NS_ + s] = acc;
}

// ---------------- K5: fused attention, scalar K/V, 8 sample-group waves ----------------
// grid: (16 qtiles, 48 bh), block 512 = 64 queries(lanes) x 8 sample-groups(waves).
__launch_bounds__(512, 2)
__global__ void attn_kernel(const float* __restrict__ qb, const float* __restrict__ kt,
                            const float* __restrict__ vt, const float* __restrict__ posb,
                            const float* __restrict__ rpe, float* __restrict__ ao)
{
    __shared__ float rp[4096];   // rpe (3969); reused: ml[1024] at 0, red float4[512] at +2048
    __shared__ float ps[512];
    const int bh = blockIdx.y;
    const int b = bh / NHD, h = bh - b * NHD;
    const int bg = b * GG + (h >> 1);
    const int tid = threadIdx.x;

    for (int e = tid; e < RPEW * RPEW; e += 512) rp[e] = rpe[(size_t)h * (RPEW * RPEW) + e];
    if (tid < 512) ps[tid] = posb[bg * 512 + tid];
    __syncthreads();

    const int q = tid & 63;
    const int sgrp = __builtin_amdgcn_readfirstlane(tid >> 6);  // wave-uniform
    const int qidx = blockIdx.x * 64 + q;
    const int row = qidx >> 5, col = qidx & 31;
    const float gyq = (float)row * (2.f / 31.f) - 1.f;
    const float gxq = (float)col * (2.f / 31.f) - 1.f;

    float qf[32];
    const float* qg = qb + ((size_t)(b * CC_ + h * HCH)) * HWSZ + qidx;
#pragma unroll
    for (int c = 0; c < 32; ++c) qf[c] = qg[(size_t)c * HWSZ];

    float m = -3.0e38f, l = 0.f;
    float oacc[32];
#pragma unroll
    for (int c = 0; c < 32; ++c) oacc[c] = 0.f;

    const float* kb2 = kt + ((size_t)bh * NS_) * 32;
    const float* vb2 = vt + ((size_t)bh * NS_) * 32;

    const int s0 = sgrp * 32;
#pragma unroll 2
    for (int s = s0; s < s0 + 32; ++s) {
        const float* kr = kb2 + s * 32;   // wave-uniform -> s_load
        float d0 = 0.f, d1 = 0.f, d2 = 0.f, d3 = 0.f;
#pragma unroll
        for (int c8 = 0; c8 < 4; ++c8) {
            const int o = c8 * 8;
            float k0 = kr[o + 0], k1 = kr[o + 1], k2 = kr[o + 2], k3 = kr[o + 3];
            float k4 = kr[o + 4], k5 = kr[o + 5], k6 = kr[o + 6], k7 = kr[o + 7];
            d0 = fmaf(qf[o + 0], k0, d0); d1 = fmaf(qf[o + 1], k1, d1);
            d2 = fmaf(qf[o + 2], k2, d2); d3 = fmaf(qf[o + 3], k3, d3);
            d0 = fmaf(qf[o + 4], k4, d0); d1 = fmaf(qf[o + 5], k5, d1);
            d2 = fmaf(qf[o + 6], k6, d2); d3 = fmaf(qf[o + 7], k7, d3);
        }
        float dot = (d0 + d1) + (d2 + d3);

        float py = ps[s * 2 + 0], px = ps[s * 2 + 1];
        float dy = (gyq - py) * 0.5f, dx = (gxq - px) * 0.5f;
        float yi = (dy + 1.f) * 31.f, xi = (dx + 1.f) * 31.f;
        float y0f = floorf(yi), x0f = floorf(xi);
        int y0 = (int)y0f, x0 = (int)x0f;
        float wy1 = yi - y0f, wx1 = xi - x0f;
        float bias = 0.f;
#pragma unroll
        for (int tt = 0; tt < 4; ++tt) {
            int iy = y0 + (tt >> 1), ix = x0 + (tt & 1);
            float wgt = ((tt >> 1) ? wy1 : 1.f - wy1) * ((tt & 1) ? wx1 : 1.f - wx1);
            if (iy >= 0 && iy <= 62 && ix >= 0 && ix <= 62)
                bias = fmaf(rp[iy * 63 + ix], wgt, bias);
        }
        float logit = fmaf(dot, SCALE_, bias);
        // deferred-max (T13): rescale only when some lane exceeds m+8 (wave-uniform branch)
        if (!__all(logit <= m + 8.f)) {
            float mnew = fmaxf(m, logit);
            float corr = __expf(m - mnew);
            l *= corr;
#pragma unroll
            for (int c = 0; c < 32; ++c) oacc[c] *= corr;
            m = mnew;
        }
        float p = __expf(logit - m);
        l += p;
        const float* vr = vb2 + s * 32;   // wave-uniform -> s_load
#pragma unroll
        for (int c8 = 0; c8 < 4; ++c8) {
            const int o = c8 * 8;
            float v0 = vr[o + 0], v1 = vr[o + 1], v2 = vr[o + 2], v3 = vr[o + 3];
            float v4 = vr[o + 4], v5 = vr[o + 5], v6 = vr[o + 6], v7 = vr[o + 7];
            oacc[o + 0] = fmaf(p, v0, oacc[o + 0]); oacc[o + 1] = fmaf(p, v1, oacc[o + 1]);
            oacc[o + 2] = fmaf(p, v2, oacc[o + 2]); oacc[o + 3] = fmaf(p, v3, oacc[o + 3]);
            oacc[o + 4] = fmaf(p, v4, oacc[o + 4]); oacc[o + 5] = fmaf(p, v5, oacc[o + 5]);
            oacc[o + 6] = fmaf(p, v6, oacc[o + 6]); oacc[o + 7] = fmaf(p, v7, oacc[o + 7]);
        }
    }

    // ---- merge 8 sample-group waves (rp dead now) ----
    __syncthreads();
    float* ml = rp;
    ml[tid * 2 + 0] = m;
    ml[tid * 2 + 1] = l;
    __syncthreads();
    float mstar = -3.0e38f;
#pragma unroll
    for (int j = 0; j < 8; ++j) mstar = fmaxf(mstar, ml[(q + 64 * j) * 2]);
    float L = 0.f;
#pragma unroll
    for (int j = 0; j < 8; ++j) {
        float mj = ml[(q + 64 * j) * 2], lj = ml[(q + 64 * j) * 2 + 1];
        L += lj * __expf(mj - mstar);
    }
    float scale = __expf(m - mstar) / L;

    float4* red = (float4*)(rp + 2048);
    float* og = ao + ((size_t)(b * CC_ + h * HCH)) * HWSZ + qidx;
#pragma unroll
    for (int cb = 0; cb < 8; ++cb) {
        __syncthreads();
        red[tid] = make_float4(oacc[cb * 4 + 0] * scale, oacc[cb * 4 + 1] * scale,
                               oacc[cb * 4 + 2] * scale, oacc[cb * 4 + 3] * scale);
        __syncthreads();
        if (sgrp == 0) {
            float4 sm = red[q];
#pragma unroll
            for (int j = 1; j < 8; ++j) {
                float4 a = red[q + 64 * j];
                sm.x += a.x; sm.y += a.y; sm.z += a.z; sm.w += a.w;
            }
            og[(size_t)(cb * 4 + 0) * HWSZ] = sm.x;
            og[(size_t)(cb * 4 + 1) * HWSZ] = sm.y;
            og[(size_t)(cb * 4 + 2) * HWSZ] = sm.z;
            og[(size_t)(cb * 4 + 3) * HWSZ] = sm.w;
        }
    }
}

extern "C" void kernel_launch(void* const* d_in, const int* in_sizes, int n_in,
                              void* d_out, int out_size, void* d_ws, size_t ws_size,
                              hipStream_t stream) {
    (void)in_sizes; (void)n_in; (void)out_size; (void)ws_size;
    const float* x   = (const float*)d_in[0];
    const float* Wq  = (const float*)d_in[1];
    const float* bq  = (const float*)d_in[2];
    const float* Wk  = (const float*)d_in[3];
    const float* bk  = (const float*)d_in[4];
    const float* Wv  = (const float*)d_in[5];
    const float* bv  = (const float*)d_in[6];
    const float* Wo  = (const float*)d_in[7];
    const float* bo  = (const float*)d_in[8];
    const float* dww = (const float*)d_in[9];
    const float* dwb = (const float*)d_in[10];
    const float* lng = (const float*)d_in[11];
    const float* lnb = (const float*)d_in[12];
    const float* pww = (const float*)d_in[13];
    const float* rpe = (const float*)d_in[14];
    float* out = (float*)d_out;

    float* ws   = (float*)d_ws;
    float* qbuf = ws;                       // 1572864
    float* posb = qbuf + 1572864;           // 12288
    float* xsb  = posb + 12288;             // 393216
    float* ktb  = xsb + 393216;             // 393216 [bh][s][32]
    float* vtb  = ktb + 393216;             // 393216 [bh][s][32]
    float* aout = vtb + 393216;             // 1572864
    float* cobuf = aout;                    // 393216, dead before attn writes aout

    conv1x1_kernel<CC_><<<dim3(1, CC_ / 4, BB), 256, 0, stream>>>(Wq, bq, x, qbuf, HWSZ, CC_);
    offset_dw_kernel<<<dim3(NGC_, 24), 256, 0, stream>>>(qbuf, dww, dwb, cobuf);
    offset_fin_kernel<<<dim3(1536), 256, 0, stream>>>(cobuf, lng, lnb, pww, posb);
    sample_xs_kernel<<<dim3(NGC_, 24), 256, 0, stream>>>(x, posb, xsb);
    conv1x1t_kernel<CC_><<<dim3(1, CC_ / 4, BB), 64, 0, stream>>>(Wk, bk, xsb, ktb, NS_, CC_);
    conv1x1t_kernel<CC_><<<dim3(1, CC_ / 4, BB), 64, 0, stream>>>(Wv, bv, xsb, vtb, NS_, CC_);
    attn_kernel<<<dim3(16, BB * NHD), 512, 0, stream>>>(qbuf, ktb, vtb, posb, rpe, aout);
    conv1x1_kernel<CC_><<<dim3(1, CC_ / 4, BB), 256, 0, stream>>>(Wo, bo, aout, out, HWSZ, CC_);
}